// Round 1
// 788.550 us; speedup vs baseline: 1.1009x; 1.1009x over previous
//
#include <hip/hip_runtime.h>

typedef __attribute__((ext_vector_type(8))) short s8v;
typedef __attribute__((ext_vector_type(4))) short s4v;
typedef __attribute__((ext_vector_type(4))) float f4v;

__device__ __forceinline__ float b2f(unsigned short b) {
  union { unsigned u; float f; } x; x.u = ((unsigned)b) << 16; return x.f;
}
__device__ __forceinline__ unsigned short f2b(float f) {
  union { float f; unsigned u; } x; x.f = f;
  unsigned r = x.u + 0x7fffu + ((x.u >> 16) & 1u);
  return (unsigned short)(r >> 16);
}
__device__ __forceinline__ void gl_lds16(const void* g, void* l) {
  __builtin_amdgcn_global_load_lds(
      (const __attribute__((address_space(1))) unsigned int*)g,
      (__attribute__((address_space(3))) unsigned int*)l, 16, 0, 0);
}

// ---------------- column-norm (sum of squares over rows) ----------------
__global__ void colsq(const float* __restrict__ W, float* __restrict__ out, int K) {
  int j = blockIdx.x * 256 + threadIdx.x;
  const float* p = W + (long)(blockIdx.y * 64) * K + j;
  float s = 0.f;
#pragma unroll 4
  for (int n = 0; n < 64; ++n) { float v = p[(long)n * K]; s += v * v; }
  atomicAdd(&out[j], s);
}

// ---------------- weight convert: bf16(W * rsqrt(colsum)) ----------------
__global__ void convw(const float* __restrict__ src, const float* __restrict__ cs,
                      unsigned short* __restrict__ dst, int Kmask) {
  long idx = ((long)blockIdx.x * 256 + threadIdx.x) << 2;
  float4 v = *(const float4*)(src + idx);
  int j = (int)(idx & (long)Kmask);
  s4v o;
  o[0] = (short)f2b(v.x * rsqrtf(cs[j]));
  o[1] = (short)f2b(v.y * rsqrtf(cs[j + 1]));
  o[2] = (short)f2b(v.z * rsqrtf(cs[j + 2]));
  o[3] = (short)f2b(v.w * rsqrtf(cs[j + 3]));
  *(s4v*)(dst + idx) = o;
}

__global__ void castf2b(const float* __restrict__ src, unsigned short* __restrict__ dst) {
  long idx = ((long)blockIdx.x * 256 + threadIdx.x) << 2;
  float4 v = *(const float4*)(src + idx);
  s4v o;
  o[0] = (short)f2b(v.x); o[1] = (short)f2b(v.y);
  o[2] = (short)f2b(v.z); o[3] = (short)f2b(v.w);
  *(s4v*)(dst + idx) = o;
}

// ---------------- generic 128x128 bf16 NT GEMM: C[m,n] = sum_k A[m,k]B[n,k] ----------------
__global__ __launch_bounds__(256) void gemm_bt(
    const unsigned short* __restrict__ A, const unsigned short* __restrict__ B,
    unsigned short* __restrict__ Cout, int K, int ldc) {
  __shared__ unsigned short smem[17408];
  unsigned short* Alds = smem;
  unsigned short* Blds = smem + 4096;
  const int tid = threadIdx.x, lane = tid & 63, w = tid >> 6;
  const int quad = lane >> 4, lq = lane & 15;
  const int wy = w >> 1, wx = w & 1;
  const int m0 = blockIdx.y << 7, n0 = blockIdx.x << 7;

  const int e0 = tid << 3;
  const int c_lo = e0 >> 10;
  const int row_s = (e0 & 1023) >> 3;
  const unsigned short* Ag = A + (long)(m0 + row_s) * K + (c_lo << 3);
  const unsigned short* Bg = B + (long)(n0 + row_s) * K + (c_lo << 3);

  f4v acc[4][4];
  f4v zero = {0.f, 0.f, 0.f, 0.f};
#pragma unroll
  for (int i = 0; i < 4; ++i)
#pragma unroll
    for (int j = 0; j < 4; ++j) acc[i][j] = zero;

  const int abase = quad * 1024 + (wy * 64 + lq) * 8;
  const int bbase = quad * 1024 + (wx * 64 + lq) * 8;

  for (int kt = 0; kt < K; kt += 32) {
    __syncthreads();
    gl_lds16(Ag + kt, Alds + e0);
    gl_lds16(Ag + kt + 16, Alds + 2048 + e0);
    gl_lds16(Bg + kt, Blds + e0);
    gl_lds16(Bg + kt + 16, Blds + 2048 + e0);
    __syncthreads();
    s8v a[4], b[4];
#pragma unroll
    for (int i = 0; i < 4; ++i) a[i] = *(const s8v*)(Alds + abase + i * 128);
#pragma unroll
    for (int j = 0; j < 4; ++j) b[j] = *(const s8v*)(Blds + bbase + j * 128);
#pragma unroll
    for (int i = 0; i < 4; ++i)
#pragma unroll
      for (int j = 0; j < 4; ++j)
        acc[i][j] = __builtin_amdgcn_mfma_f32_16x16x32_bf16(a[i], b[j], acc[i][j], 0, 0, 0);
  }
  __syncthreads();
#pragma unroll
  for (int i = 0; i < 4; ++i)
#pragma unroll
    for (int j = 0; j < 4; ++j)
#pragma unroll
      for (int r = 0; r < 4; ++r) {
        int row = wy * 64 + i * 16 + quad * 4 + r;
        int col = wx * 64 + j * 16 + lq;
        smem[row * 136 + col] = f2b(acc[i][j][r]);
      }
  __syncthreads();
#pragma unroll
  for (int it = 0; it < 8; ++it) {
    int row = it * 16 + (tid >> 4);
    int col = (tid & 15) << 3;
    s8v v = *(const s8v*)(smem + row * 136 + col);
    *(s8v*)(Cout + (long)(m0 + row) * ldc + n0 + col) = v;
  }
}

// ---------------- Wfc GEMM fused with SwiGLU, 256x256 tile, 4-deep pipeline ----------------
// Block: 256 M-rows x 128 X-cols (u rows n0..n0+127, v rows 4096+n0..+127).
// 512 thr = 8 waves (2M x 4N). BK=32, 4 LDS ring buffers (128 KB), counted vmcnt,
// XOR-swizzled LDS reads (T2, via pre-swizzled global source), setprio (T5).
__global__ __launch_bounds__(512, 2) void gemm_fc(
    const unsigned short* __restrict__ A, const unsigned short* __restrict__ B,
    unsigned short* __restrict__ X, const float* __restrict__ suv) {
  __shared__ unsigned short smem[65536];  // 128 KB: 4 bufs x (A 16KB | B 16KB)
  const int tid = threadIdx.x, lane = tid & 63, w = tid >> 6;
  const int quad = lane >> 4, lq = lane & 15;
  const int wy = w >> 2, wx = w & 3;  // 2 x 4 wave grid
  const int bid = blockIdx.x;
  const int swzb = ((bid & 7) << 7) | (bid >> 3);  // XCD swizzle, 1024 % 8 == 0
  const int m0 = (swzb >> 5) << 8;
  const int n0 = (swzb & 31) << 7;

  // read-side swizzle: byte ^= ((row>>1)&3)<<4  (row = ...+lq, bases are mult of 8)
  const int swz = ((lq >> 1) & 3) << 4;
  const int aoff = wy * 8192 + lq * 64 + ((quad * 16) ^ swz);
  const int boff = 16384 + wx * 2048 + lq * 64 + ((quad * 16) ^ swz);

  // stage side: linear LDS dest (gl_lds requirement), inverse-swizzled global col
  const int trow = tid >> 2;
  const int cb = ((tid & 3) ^ ((tid >> 3) & 3)) << 3;
  const unsigned short* Ag0 = A + (long)(m0 + trow) * 1024 + cb;
  const unsigned short* Ag1 = A + (long)(m0 + 128 + trow) * 1024 + cb;
  const unsigned short* Bg0 = B + (long)(n0 + trow) * 1024 + cb;
  const unsigned short* Bg1 = B + (long)(4096 + n0 + trow) * 1024 + cb;
  unsigned short* l0 = smem + (tid << 3);

  float su[2], sv[2];
#pragma unroll
  for (int j = 0; j < 2; ++j) {
    su[j] = suv[n0 + wx * 32 + j * 16 + lq] * 32.f;
    sv[j] = suv[4096 + n0 + wx * 32 + j * 16 + lq] * 32.f;
  }

  f4v aU[8][2], aV[8][2];
  f4v zero = {0.f, 0.f, 0.f, 0.f};
#pragma unroll
  for (int m = 0; m < 8; ++m)
#pragma unroll
    for (int j = 0; j < 2; ++j) { aU[m][j] = zero; aV[m][j] = zero; }

  auto stage = [&](int T) {
    const int bo = (T & 3) << 14;  // halfword offset of ring buffer
    const int col = T << 5;
    gl_lds16(Ag0 + col, l0 + bo);
    gl_lds16(Ag1 + col, l0 + bo + 4096);
    gl_lds16(Bg0 + col, l0 + bo + 8192);
    gl_lds16(Bg1 + col, l0 + bo + 12288);
  };

  const char* sb = (const char*)smem;
  auto compute = [&](int kt) {
    const int bo = (kt & 3) << 15;  // byte offset of ring buffer
    s8v bu0 = *(const s8v*)(sb + bo + boff);
    s8v bu1 = *(const s8v*)(sb + bo + boff + 1024);
    s8v bv0 = *(const s8v*)(sb + bo + boff + 8192);
    s8v bv1 = *(const s8v*)(sb + bo + boff + 9216);
    s8v av[8];
#pragma unroll
    for (int m = 0; m < 8; ++m) av[m] = *(const s8v*)(sb + bo + aoff + m * 1024);
    __builtin_amdgcn_s_setprio(1);
#pragma unroll
    for (int m = 0; m < 8; ++m) {
      aU[m][0] = __builtin_amdgcn_mfma_f32_16x16x32_bf16(av[m], bu0, aU[m][0], 0, 0, 0);
      aV[m][0] = __builtin_amdgcn_mfma_f32_16x16x32_bf16(av[m], bv0, aV[m][0], 0, 0, 0);
      aU[m][1] = __builtin_amdgcn_mfma_f32_16x16x32_bf16(av[m], bu1, aU[m][1], 0, 0, 0);
      aV[m][1] = __builtin_amdgcn_mfma_f32_16x16x32_bf16(av[m], bv1, aV[m][1], 0, 0, 0);
    }
    __builtin_amdgcn_s_setprio(0);
  };

  // Prologue: tiles 0..2 in flight (12 loads). Invariant at tile kt's wait:
  // exactly 8 loads (tiles kt+1, kt+2) are younger than tile kt -> vmcnt(8)
  // retires tile kt for THIS wave; barrier makes it global.
  stage(0); stage(1); stage(2);
  for (int kt = 0; kt < 30; ++kt) {
    asm volatile("s_waitcnt vmcnt(8)" ::: "memory");
    __builtin_amdgcn_s_barrier();
    asm volatile("" ::: "memory");
    if (kt < 29) stage(kt + 3);  // buf (kt+3)&3 == (kt-1)&3, freed by this barrier
    compute(kt);
  }
  asm volatile("s_waitcnt vmcnt(4)" ::: "memory");
  __builtin_amdgcn_s_barrier();
  asm volatile("" ::: "memory");
  compute(30);
  asm volatile("s_waitcnt vmcnt(0)" ::: "memory");
  __builtin_amdgcn_s_barrier();
  asm volatile("" ::: "memory");
  compute(31);

  __syncthreads();
  // swiglu epilogue -> LDS staging [256][132] (pad: quads land 8 banks apart)
#pragma unroll
  for (int m = 0; m < 8; ++m)
#pragma unroll
    for (int j = 0; j < 2; ++j)
#pragma unroll
      for (int r = 0; r < 4; ++r) {
        int row = wy * 128 + m * 16 + quad * 4 + r;
        int col = wx * 32 + j * 16 + lq;
        float uu = aU[m][j][r] * su[j];
        float vg = aV[m][j][r] * sv[j];
        float sig = 1.f / (1.f + __builtin_amdgcn_exp2f(vg * -1.44269504f));
        smem[row * 132 + col] = f2b(uu * vg * sig);
      }
  __syncthreads();
  {
    const int row = tid >> 1, half = tid & 1;
    unsigned short* dst = X + (long)(m0 + row) * 4096 + n0 + half * 64;
    const unsigned short* srcr = smem + row * 132 + half * 64;
#pragma unroll
    for (int s = 0; s < 8; ++s)
      *(s8v*)(dst + s * 8) = *(const s8v*)(srcr + s * 8);
  }
}

// ---------------- qkv post-process: justnorm q,k (in-place, *sqk*32), V -> Vt[BH,D,T] ----------------
__global__ __launch_bounds__(256) void qkv_norm(unsigned short* __restrict__ qkv,
                                                unsigned short* __restrict__ Vt,
                                                const float* __restrict__ sqk) {
  __shared__ unsigned short tl[64][72];
  const int tid = threadIdx.x;
  const int blk = blockIdx.x;
  const int tt = blk & 15, bh = blk >> 4, b = bh >> 4, h = bh & 15;
  const int t0 = tt << 6;
  const int r = tid >> 2, seg = tid & 3;
  float sc[16];
#pragma unroll
  for (int c = 0; c < 16; ++c) sc[c] = sqk[h * 64 + seg * 16 + c] * 32.f;
  for (int which = 0; which < 2; ++which) {
    unsigned short* p = qkv + (long)(b * 1024 + t0 + r) * 3072 + which * 1024 + h * 64 + seg * 16;
    s8v x0 = *(const s8v*)p, x1 = *(const s8v*)(p + 8);
    float ss = 0.f;
#pragma unroll
    for (int c = 0; c < 8; ++c) {
      float a = b2f((unsigned short)x0[c]), bb = b2f((unsigned short)x1[c]);
      ss += a * a + bb * bb;
    }
    ss += __shfl_xor(ss, 1, 64);
    ss += __shfl_xor(ss, 2, 64);
    float rn = rsqrtf(ss);
#pragma unroll
    for (int c = 0; c < 8; ++c) {
      x0[c] = (short)f2b(b2f((unsigned short)x0[c]) * rn * sc[c]);
      x1[c] = (short)f2b(b2f((unsigned short)x1[c]) * rn * sc[c + 8]);
    }
    *(s8v*)p = x0; *(s8v*)(p + 8) = x1;
  }
  {
    const unsigned short* p = qkv + (long)(b * 1024 + t0 + r) * 3072 + 2048 + h * 64 + seg * 16;
    s8v v0 = *(const s8v*)p, v1 = *(const s8v*)(p + 8);
#pragma unroll
    for (int c = 0; c < 8; ++c) {
      tl[seg * 16 + c][r] = (unsigned short)v0[c];
      tl[seg * 16 + 8 + c][r] = (unsigned short)v1[c];
    }
  }
  __syncthreads();
  {
    const int d = tid >> 2, part = tid & 3;
    s8v o0 = *(const s8v*)(&tl[d][part * 16]);
    s8v o1 = *(const s8v*)(&tl[d][part * 16 + 8]);
    unsigned short* q = Vt + (long)(bh * 64 + d) * 1024 + t0 + part * 16;
    *(s8v*)q = o0; *(s8v*)(q + 8) = o1;
  }
}

// ---------------- flash attention (non-causal, bounded logits -> no running max) ----------------
__global__ __launch_bounds__(256) void attn(const unsigned short* __restrict__ qkv,
                                            const unsigned short* __restrict__ Vt,
                                            unsigned short* __restrict__ Y) {
  __shared__ unsigned short smem[33792];
  unsigned short* Klds = smem;
  unsigned short* Vlds = smem + 8192;
  unsigned short* Plds = smem + 16384;
  const int tid = threadIdx.x, lane = tid & 63, w = tid >> 6;
  const int quad = lane >> 4, lq = lane & 15;
  const int bh = blockIdx.x, b = bh >> 4, h = bh & 15;
  const int qt = blockIdx.y;
  const int e0 = tid << 3;
  const int c_lo = e0 >> 10, row_s = (e0 & 1023) >> 3;
  const int vc_lo = e0 >> 9, vd = (e0 & 511) >> 3;

  s8v qf[2][2];
#pragma unroll
  for (int i = 0; i < 2; ++i)
#pragma unroll
    for (int ks = 0; ks < 2; ++ks) {
      int row = qt * 128 + w * 32 + i * 16 + lq;
      qf[i][ks] = *(const s8v*)(qkv + (long)(b * 1024 + row) * 3072 + h * 64 + ks * 32 + quad * 8);
    }

  f4v o[2][4];
  float lp[2][4];
  f4v zero = {0.f, 0.f, 0.f, 0.f};
#pragma unroll
  for (int i = 0; i < 2; ++i) {
#pragma unroll
    for (int nf = 0; nf < 4; ++nf) o[i][nf] = zero;
#pragma unroll
    for (int r = 0; r < 4; ++r) lp[i][r] = 0.f;
  }

  const unsigned short* Kg = qkv + (long)(b * 1024 + row_s) * 3072 + 1024 + h * 64 + (c_lo << 3);
  const unsigned short* Vg = Vt + (long)(bh * 64 + vd) * 1024 + (vc_lo << 3);
  unsigned short* Pw = Plds + w * 4352;

  for (int kt0 = 0; kt0 < 1024; kt0 += 128) {
    __syncthreads();
#pragma unroll
    for (int it = 0; it < 4; ++it) {
      gl_lds16(Kg + (long)kt0 * 3072 + it * 16, Klds + it * 2048 + e0);
      gl_lds16(Vg + kt0 + it * 32, Vlds + it * 2048 + e0);
    }
    __syncthreads();
    f4v s[2][8];
#pragma unroll
    for (int i = 0; i < 2; ++i)
#pragma unroll
      for (int j = 0; j < 8; ++j) s[i][j] = zero;
#pragma unroll
    for (int ks = 0; ks < 2; ++ks)
#pragma unroll
      for (int j = 0; j < 8; ++j) {
        s8v kf = *(const s8v*)(Klds + (ks * 4 + quad) * 1024 + (j * 16 + lq) * 8);
        s[0][j] = __builtin_amdgcn_mfma_f32_16x16x32_bf16(qf[0][ks], kf, s[0][j], 0, 0, 0);
        s[1][j] = __builtin_amdgcn_mfma_f32_16x16x32_bf16(qf[1][ks], kf, s[1][j], 0, 0, 0);
      }
#pragma unroll
    for (int i = 0; i < 2; ++i)
#pragma unroll
      for (int j = 0; j < 8; ++j)
#pragma unroll
        for (int r = 0; r < 4; ++r) {
          float p = __builtin_amdgcn_exp2f(s[i][j][r] * 11.5415603f - 11.5415603f);
          lp[i][r] += p;
          Pw[(i * 16 + quad * 4 + r) * 136 + j * 16 + lq] = f2b(p);
        }
    s8v pf[2][4];
#pragma unroll
    for (int i = 0; i < 2; ++i)
#pragma unroll
      for (int ks = 0; ks < 4; ++ks)
        pf[i][ks] = *(const s8v*)(Pw + (i * 16 + lq) * 136 + ks * 32 + quad * 8);
#pragma unroll
    for (int nf = 0; nf < 4; ++nf)
#pragma unroll
      for (int ks = 0; ks < 4; ++ks) {
        s8v vf = *(const s8v*)(Vlds + (ks * 4 + quad) * 512 + (nf * 16 + lq) * 8);
        o[0][nf] = __builtin_amdgcn_mfma_f32_16x16x32_bf16(pf[0][ks], vf, o[0][nf], 0, 0, 0);
        o[1][nf] = __builtin_amdgcn_mfma_f32_16x16x32_bf16(pf[1][ks], vf, o[1][nf], 0, 0, 0);
      }
  }
#pragma unroll
  for (int i = 0; i < 2; ++i)
#pragma unroll
    for (int r = 0; r < 4; ++r) {
      float v = lp[i][r];
      v += __shfl_xor(v, 1, 64); v += __shfl_xor(v, 2, 64);
      v += __shfl_xor(v, 4, 64); v += __shfl_xor(v, 8, 64);
      lp[i][r] = 1.f / v;
    }
#pragma unroll
  for (int i = 0; i < 2; ++i)
#pragma unroll
    for (int nf = 0; nf < 4; ++nf)
#pragma unroll
      for (int r = 0; r < 4; ++r) {
        int row = qt * 128 + w * 32 + i * 16 + quad * 4 + r;
        Y[(long)(b * 1024 + row) * 1024 + h * 64 + nf * 16 + lq] = f2b(o[i][nf][r] * lp[i][r]);
      }
}

// ---------------- spherical-lerp residual: out = justnorm(A + |alpha*1.6|*(Bn - A)) ----------------
__global__ __launch_bounds__(256) void residual(
    const float* __restrict__ hin, const unsigned short* __restrict__ hbr,
    const float* __restrict__ alpha, float* __restrict__ outf,
    unsigned short* __restrict__ outb) {
  __shared__ float red[8];
  const int tid = threadIdx.x, lane = tid & 63, w = tid >> 6;
  const long base = (long)blockIdx.x * 1024;
  float hv[4], bvv[4];
  float s1 = 0.f, s2 = 0.f;
#pragma unroll
  for (int k = 0; k < 4; ++k) {
    int c = k * 256 + tid;
    hv[k] = hin[base + c];
    bvv[k] = b2f(hbr[base + c]);
    s1 += hv[k] * hv[k]; s2 += bvv[k] * bvv[k];
  }
#pragma unroll
  for (int m = 1; m < 64; m <<= 1) { s1 += __shfl_xor(s1, m, 64); s2 += __shfl_xor(s2, m, 64); }
  if (lane == 0) { red[w] = s1; red[4 + w] = s2; }
  __syncthreads();
  s1 = red[0] + red[1] + red[2] + red[3];
  s2 = red[4] + red[5] + red[6] + red[7];
  float rn1 = rsqrtf(s1), rn2 = rsqrtf(s2);
  float z[4], s3 = 0.f;
#pragma unroll
  for (int k = 0; k < 4; ++k) {
    int c = k * 256 + tid;
    float a = hv[k] * rn1;
    float lr = fabsf(alpha[c]) * 1.6f;
    float zz = a + lr * (bvv[k] * rn2 - a);
    z[k] = zz; s3 += zz * zz;
  }
#pragma unroll
  for (int m = 1; m < 64; m <<= 1) s3 += __shfl_xor(s3, m, 64);
  __syncthreads();
  if (lane == 0) red[w] = s3;
  __syncthreads();
  s3 = red[0] + red[1] + red[2] + red[3];
  float rn3 = rsqrtf(s3);
#pragma unroll
  for (int k = 0; k < 4; ++k) {
    int c = k * 256 + tid;
    float ov = z[k] * rn3;
    if (outf) outf[base + c] = ov;
    if (outb) outb[base + c] = f2b(ov);
  }
}

extern "C" void kernel_launch(void* const* d_in, const int* in_sizes, int n_in,
                              void* d_out, int out_size, void* d_ws, size_t ws_size,
                              hipStream_t stream) {
  const float* h   = (const float*)d_in[0];
  const float* Wq  = (const float*)d_in[1];
  const float* Wk  = (const float*)d_in[2];
  const float* Wv  = (const float*)d_in[3];
  const float* Wo  = (const float*)d_in[4];
  const float* Wfc = (const float*)d_in[5];
  const float* Wpj = (const float*)d_in[6];
  const float* sqk = (const float*)d_in[7];
  const float* suv = (const float*)d_in[8];
  const float* aat = (const float*)d_in[9];
  const float* aml = (const float*)d_in[10];
  float* out = (float*)d_out;  // reference output dtype is float32

  char* ws = (char*)d_ws;
  size_t off = 0;
  auto alloc = [&](size_t n) { char* p = ws + off; off += (n + 255) & ~(size_t)255; return p; };
  float* cs_q  = (float*)alloc(4096);
  float* cs_k  = (float*)alloc(4096);
  float* cs_v  = (float*)alloc(4096);
  float* cs_o  = (float*)alloc(4096);
  unsigned short* Wqkv_b = (unsigned short*)alloc(3ull * 1024 * 1024 * 2);
  unsigned short* Wo_b   = (unsigned short*)alloc(1024ull * 1024 * 2);
  unsigned short* Wfc_b  = (unsigned short*)alloc(8192ull * 1024 * 2);   // RAW (no col-norm)
  unsigned short* Wpj_b  = (unsigned short*)alloc(1024ull * 4096 * 2);   // RAW (no col-norm)
  unsigned short* slotC  = (unsigned short*)alloc(8192ull * 1024 * 2);   // h_b -> h_mlp
  unsigned short* slotD  = (unsigned short*)alloc(8192ull * 4096 * 2);   // qkv -> xmlp; hatt at +48MB
  unsigned short* slotE  = (unsigned short*)alloc(8192ull * 1024 * 2);   // Vt -> h2_b
  unsigned short* y_b    = (unsigned short*)alloc(8192ull * 1024 * 2);
  float*          h2_f   = (float*)alloc(8192ull * 1024 * 4);

  unsigned short* h_b    = slotC;
  unsigned short* hmlp_b = slotC;
  unsigned short* qkv_r  = slotD;
  unsigned short* xmlp   = slotD;
  unsigned short* hatt_b = slotD + 25165824;  // byte 48MB..64MB of slotD (qkv dead after attn)
  unsigned short* Vt     = slotE;
  unsigned short* h2_b   = slotE;

  hipMemsetAsync(ws, 0, 16384, stream);
  colsq<<<dim3(4, 16), 256, 0, stream>>>(Wq, cs_q, 1024);
  colsq<<<dim3(4, 16), 256, 0, stream>>>(Wk, cs_k, 1024);
  colsq<<<dim3(4, 16), 256, 0, stream>>>(Wv, cs_v, 1024);
  colsq<<<dim3(4, 16), 256, 0, stream>>>(Wo, cs_o, 1024);
  convw<<<1024, 256, 0, stream>>>(Wq, cs_q, Wqkv_b, 1023);
  convw<<<1024, 256, 0, stream>>>(Wk, cs_k, Wqkv_b + 1048576, 1023);
  convw<<<1024, 256, 0, stream>>>(Wv, cs_v, Wqkv_b + 2097152, 1023);
  convw<<<1024, 256, 0, stream>>>(Wo, cs_o, Wo_b, 1023);
  castf2b<<<8192, 256, 0, stream>>>(Wfc, Wfc_b);
  castf2b<<<4096, 256, 0, stream>>>(Wpj, Wpj_b);
  castf2b<<<8192, 256, 0, stream>>>(h, h_b);
  // qkv = h @ [Wq_n;Wk_n;Wv_n]^T
  gemm_bt<<<dim3(24, 64), 256, 0, stream>>>(h_b, Wqkv_b, qkv_r, 1024, 3072);
  qkv_norm<<<2048, 256, 0, stream>>>(qkv_r, Vt, sqk);
  attn<<<dim3(128, 8), 256, 0, stream>>>(qkv_r, Vt, y_b);
  // h_att = y @ Wo_n^T
  gemm_bt<<<dim3(8, 64), 256, 0, stream>>>(y_b, Wo_b, hatt_b, 1024, 1024);
  residual<<<8192, 256, 0, stream>>>(h, hatt_b, aat, h2_f, h2_b);
  // x_mlp = swiglu(h2 @ Wfc^T)  — 256x256-tile 4-deep pipelined kernel
  gemm_fc<<<1024, 512, 0, stream>>>(h2_b, Wfc_b, xmlp, suv);
  // h_mlp = x_mlp @ Wproj^T
  gemm_bt<<<dim3(8, 64), 256, 0, stream>>>(xmlp, Wpj_b, hmlp_b, 4096, 1024);
  // FINAL: write float32 to d_out
  residual<<<8192, 256, 0, stream>>>(h2_f, hmlp_b, aml, out, nullptr);
}

// Round 2
// 649.642 us; speedup vs baseline: 1.3363x; 1.2138x over previous
//
#include <hip/hip_runtime.h>

typedef __attribute__((ext_vector_type(8))) short s8v;
typedef __attribute__((ext_vector_type(4))) short s4v;
typedef __attribute__((ext_vector_type(4))) float f4v;

__device__ __forceinline__ float b2f(unsigned short b) {
  union { unsigned u; float f; } x; x.u = ((unsigned)b) << 16; return x.f;
}
__device__ __forceinline__ unsigned short f2b(float f) {
  union { float f; unsigned u; } x; x.f = f;
  unsigned r = x.u + 0x7fffu + ((x.u >> 16) & 1u);
  return (unsigned short)(r >> 16);
}
__device__ __forceinline__ void gl_lds16(const void* g, void* l) {
  __builtin_amdgcn_global_load_lds(
      (const __attribute__((address_space(1))) unsigned int*)g,
      (__attribute__((address_space(3))) unsigned int*)l, 16, 0, 0);
}

// ---------------- column-norm (sum of squares over rows) ----------------
__global__ void colsq(const float* __restrict__ W, float* __restrict__ out, int K) {
  int j = blockIdx.x * 256 + threadIdx.x;
  const float* p = W + (long)(blockIdx.y * 64) * K + j;
  float s = 0.f;
#pragma unroll 4
  for (int n = 0; n < 64; ++n) { float v = p[(long)n * K]; s += v * v; }
  atomicAdd(&out[j], s);
}

// ---------------- weight convert: bf16(W * rsqrt(colsum)) ----------------
__global__ void convw(const float* __restrict__ src, const float* __restrict__ cs,
                      unsigned short* __restrict__ dst, int Kmask) {
  long idx = ((long)blockIdx.x * 256 + threadIdx.x) << 2;
  float4 v = *(const float4*)(src + idx);
  int j = (int)(idx & (long)Kmask);
  s4v o;
  o[0] = (short)f2b(v.x * rsqrtf(cs[j]));
  o[1] = (short)f2b(v.y * rsqrtf(cs[j + 1]));
  o[2] = (short)f2b(v.z * rsqrtf(cs[j + 2]));
  o[3] = (short)f2b(v.w * rsqrtf(cs[j + 3]));
  *(s4v*)(dst + idx) = o;
}

__global__ void castf2b(const float* __restrict__ src, unsigned short* __restrict__ dst) {
  long idx = ((long)blockIdx.x * 256 + threadIdx.x) << 2;
  float4 v = *(const float4*)(src + idx);
  s4v o;
  o[0] = (short)f2b(v.x); o[1] = (short)f2b(v.y);
  o[2] = (short)f2b(v.z); o[3] = (short)f2b(v.w);
  *(s4v*)(dst + idx) = o;
}

// ---------------- 128x128 bf16 NT GEMM, 4-deep pipelined: C[m,n] = sum_k A[m,k]B[n,k] ----------------
// 256 thr = 4 waves (2M x 2N), per-wave 64x64. BK=32, 4 LDS ring bufs (64 KB -> 2 blocks/CU),
// counted vmcnt(8), both-sides XOR swizzle, setprio around MFMA cluster.
__global__ __launch_bounds__(256) void gemm_bt(
    const unsigned short* __restrict__ A, const unsigned short* __restrict__ B,
    unsigned short* __restrict__ Cout, int K, int ldc) {
  __shared__ unsigned short smem[32768];  // 64 KB: 4 bufs x (A 8KB | B 8KB)
  const int tid = threadIdx.x, lane = tid & 63, w = tid >> 6;
  const int quad = lane >> 4, lq = lane & 15;
  const int wy = w >> 1, wx = w & 1;
  const int m0 = blockIdx.y << 7, n0 = blockIdx.x << 7;

  // stage side: linear LDS dest (gl_lds), inverse-swizzled global column
  const int trow = tid >> 2;
  const int cb = ((tid & 3) ^ ((tid >> 3) & 3)) << 3;
  const unsigned short* Ag0 = A + (long)(m0 + trow) * K + cb;
  const unsigned short* Ag1 = A + (long)(m0 + 64 + trow) * K + cb;
  const unsigned short* Bg0 = B + (long)(n0 + trow) * K + cb;
  const unsigned short* Bg1 = B + (long)(n0 + 64 + trow) * K + cb;
  unsigned short* l0 = smem + (tid << 3);

  // read side: byte addr = row*64 + ((quad ^ ((row>>1)&3))<<4); frag-row bases are mult of 16
  const int swz = ((lq >> 1) & 3) << 4;
  const int aoff = (wy * 64 + lq) * 64 + ((quad << 4) ^ swz);         // + i*1024 B
  const int boff = 8192 + (wx * 64 + lq) * 64 + ((quad << 4) ^ swz);  // + j*1024 B

  f4v acc[4][4];
  f4v zero = {0.f, 0.f, 0.f, 0.f};
#pragma unroll
  for (int i = 0; i < 4; ++i)
#pragma unroll
    for (int j = 0; j < 4; ++j) acc[i][j] = zero;

  auto stage = [&](int T) {
    const int bo = (T & 3) << 13;  // halfword offset: buf*8192
    const int col = T << 5;
    gl_lds16(Ag0 + col, l0 + bo);
    gl_lds16(Ag1 + col, l0 + bo + 2048);
    gl_lds16(Bg0 + col, l0 + bo + 4096);
    gl_lds16(Bg1 + col, l0 + bo + 6144);
  };
  const char* sb = (const char*)smem;
  auto compute = [&](int kt) {
    const int bo = (kt & 3) << 14;  // byte offset: buf*16384
    s8v a[4], b[4];
#pragma unroll
    for (int i = 0; i < 4; ++i) a[i] = *(const s8v*)(sb + bo + aoff + i * 1024);
#pragma unroll
    for (int j = 0; j < 4; ++j) b[j] = *(const s8v*)(sb + bo + boff + j * 1024);
    __builtin_amdgcn_s_setprio(1);
#pragma unroll
    for (int i = 0; i < 4; ++i)
#pragma unroll
      for (int j = 0; j < 4; ++j)
        acc[i][j] = __builtin_amdgcn_mfma_f32_16x16x32_bf16(a[i], b[j], acc[i][j], 0, 0, 0);
    __builtin_amdgcn_s_setprio(0);
  };

  // Invariant at tile kt's wait: tiles kt+1, kt+2 (8 loads) are younger -> vmcnt(8)
  // retires tile kt for this wave; the barrier makes it block-wide.
  const int nt = K >> 5;
  stage(0); stage(1); stage(2);
  for (int kt = 0; kt < nt - 2; ++kt) {
    asm volatile("s_waitcnt vmcnt(8)" ::: "memory");
    __builtin_amdgcn_s_barrier();
    asm volatile("" ::: "memory");
    if (kt < nt - 3) stage(kt + 3);  // buf (kt+3)&3 == (kt-1)&3, freed by this barrier
    compute(kt);
  }
  asm volatile("s_waitcnt vmcnt(4)" ::: "memory");
  __builtin_amdgcn_s_barrier();
  asm volatile("" ::: "memory");
  compute(nt - 2);
  asm volatile("s_waitcnt vmcnt(0)" ::: "memory");
  __builtin_amdgcn_s_barrier();
  asm volatile("" ::: "memory");
  compute(nt - 1);

  __syncthreads();
#pragma unroll
  for (int i = 0; i < 4; ++i)
#pragma unroll
    for (int j = 0; j < 4; ++j)
#pragma unroll
      for (int r = 0; r < 4; ++r) {
        int row = wy * 64 + i * 16 + quad * 4 + r;
        int col = wx * 64 + j * 16 + lq;
        smem[row * 136 + col] = f2b(acc[i][j][r]);
      }
  __syncthreads();
#pragma unroll
  for (int it = 0; it < 8; ++it) {
    int row = it * 16 + (tid >> 4);
    int col = (tid & 15) << 3;
    s8v v = *(const s8v*)(smem + row * 136 + col);
    *(s8v*)(Cout + (long)(m0 + row) * ldc + n0 + col) = v;
  }
}

// ---------------- Wfc GEMM fused with SwiGLU, 256x256 tile, 4-deep pipeline ----------------
// Block: 256 M-rows x 128 X-cols (u rows n0..n0+127, v rows 4096+n0..+127).
// 512 thr = 8 waves (2M x 4N). BK=32, 4 LDS ring buffers (128 KB), counted vmcnt,
// XOR-swizzled LDS reads (T2, via pre-swizzled global source), setprio (T5).
// Per-XCD chunk is m-minor: each B panel is consumed by 4 consecutive m-tiles -> B L2-fetched
// once per XCD (~19 MB/XCD) instead of streamed 4x (~67 MB/XCD).
__global__ __launch_bounds__(512, 2) void gemm_fc(
    const unsigned short* __restrict__ A, const unsigned short* __restrict__ B,
    unsigned short* __restrict__ X, const float* __restrict__ suv) {
  __shared__ unsigned short smem[65536];  // 128 KB: 4 bufs x (A 16KB | B 16KB)
  const int tid = threadIdx.x, lane = tid & 63, w = tid >> 6;
  const int quad = lane >> 4, lq = lane & 15;
  const int wy = w >> 2, wx = w & 3;  // 2 x 4 wave grid
  const int bid = blockIdx.x;
  const int xr = bid & 7, xq = bid >> 3;  // XCD chunk, m-minor within chunk
  const int m0 = ((xr << 2) | (xq & 3)) << 8;
  const int n0 = (xq >> 2) << 7;

  // read-side swizzle: byte ^= ((row>>1)&3)<<4  (row = ...+lq, bases are mult of 8)
  const int swz = ((lq >> 1) & 3) << 4;
  const int aoff = wy * 8192 + lq * 64 + ((quad * 16) ^ swz);
  const int boff = 16384 + wx * 2048 + lq * 64 + ((quad * 16) ^ swz);

  // stage side: linear LDS dest (gl_lds requirement), inverse-swizzled global col
  const int trow = tid >> 2;
  const int cb = ((tid & 3) ^ ((tid >> 3) & 3)) << 3;
  const unsigned short* Ag0 = A + (long)(m0 + trow) * 1024 + cb;
  const unsigned short* Ag1 = A + (long)(m0 + 128 + trow) * 1024 + cb;
  const unsigned short* Bg0 = B + (long)(n0 + trow) * 1024 + cb;
  const unsigned short* Bg1 = B + (long)(4096 + n0 + trow) * 1024 + cb;
  unsigned short* l0 = smem + (tid << 3);

  float su[2], sv[2];
#pragma unroll
  for (int j = 0; j < 2; ++j) {
    su[j] = suv[n0 + wx * 32 + j * 16 + lq] * 32.f;
    sv[j] = suv[4096 + n0 + wx * 32 + j * 16 + lq] * 32.f;
  }

  f4v aU[8][2], aV[8][2];
  f4v zero = {0.f, 0.f, 0.f, 0.f};
#pragma unroll
  for (int m = 0; m < 8; ++m)
#pragma unroll
    for (int j = 0; j < 2; ++j) { aU[m][j] = zero; aV[m][j] = zero; }

  auto stage = [&](int T) {
    const int bo = (T & 3) << 14;  // halfword offset of ring buffer
    const int col = T << 5;
    gl_lds16(Ag0 + col, l0 + bo);
    gl_lds16(Ag1 + col, l0 + bo + 4096);
    gl_lds16(Bg0 + col, l0 + bo + 8192);
    gl_lds16(Bg1 + col, l0 + bo + 12288);
  };

  const char* sb = (const char*)smem;
  auto compute = [&](int kt) {
    const int bo = (kt & 3) << 15;  // byte offset of ring buffer
    s8v bu0 = *(const s8v*)(sb + bo + boff);
    s8v bu1 = *(const s8v*)(sb + bo + boff + 1024);
    s8v bv0 = *(const s8v*)(sb + bo + boff + 8192);
    s8v bv1 = *(const s8v*)(sb + bo + boff + 9216);
    s8v av[8];
#pragma unroll
    for (int m = 0; m < 8; ++m) av[m] = *(const s8v*)(sb + bo + aoff + m * 1024);
    __builtin_amdgcn_s_setprio(1);
#pragma unroll
    for (int m = 0; m < 8; ++m) {
      aU[m][0] = __builtin_amdgcn_mfma_f32_16x16x32_bf16(av[m], bu0, aU[m][0], 0, 0, 0);
      aV[m][0] = __builtin_amdgcn_mfma_f32_16x16x32_bf16(av[m], bv0, aV[m][0], 0, 0, 0);
      aU[m][1] = __builtin_amdgcn_mfma_f32_16x16x32_bf16(av[m], bu1, aU[m][1], 0, 0, 0);
      aV[m][1] = __builtin_amdgcn_mfma_f32_16x16x32_bf16(av[m], bv1, aV[m][1], 0, 0, 0);
    }
    __builtin_amdgcn_s_setprio(0);
  };

  // Prologue: tiles 0..2 in flight (12 loads). vmcnt(8) retires tile kt at its wait.
  stage(0); stage(1); stage(2);
  for (int kt = 0; kt < 30; ++kt) {
    asm volatile("s_waitcnt vmcnt(8)" ::: "memory");
    __builtin_amdgcn_s_barrier();
    asm volatile("" ::: "memory");
    if (kt < 29) stage(kt + 3);  // buf (kt+3)&3 == (kt-1)&3, freed by this barrier
    compute(kt);
  }
  asm volatile("s_waitcnt vmcnt(4)" ::: "memory");
  __builtin_amdgcn_s_barrier();
  asm volatile("" ::: "memory");
  compute(30);
  asm volatile("s_waitcnt vmcnt(0)" ::: "memory");
  __builtin_amdgcn_s_barrier();
  asm volatile("" ::: "memory");
  compute(31);

  __syncthreads();
  // swiglu epilogue -> LDS staging [256][132] (pad: quads land 8 banks apart)
#pragma unroll
  for (int m = 0; m < 8; ++m)
#pragma unroll
    for (int j = 0; j < 2; ++j)
#pragma unroll
      for (int r = 0; r < 4; ++r) {
        int row = wy * 128 + m * 16 + quad * 4 + r;
        int col = wx * 32 + j * 16 + lq;
        float uu = aU[m][j][r] * su[j];
        float vg = aV[m][j][r] * sv[j];
        float sig = 1.f / (1.f + __builtin_amdgcn_exp2f(vg * -1.44269504f));
        smem[row * 132 + col] = f2b(uu * vg * sig);
      }
  __syncthreads();
  {
    const int row = tid >> 1, half = tid & 1;
    unsigned short* dst = X + (long)(m0 + row) * 4096 + n0 + half * 64;
    const unsigned short* srcr = smem + row * 132 + half * 64;
#pragma unroll
    for (int s = 0; s < 8; ++s)
      *(s8v*)(dst + s * 8) = *(const s8v*)(srcr + s * 8);
  }
}

// ---------------- qkv post-process: justnorm q,k (in-place, *sqk*32), V -> Vt[BH,D,T] ----------------
__global__ __launch_bounds__(256) void qkv_norm(unsigned short* __restrict__ qkv,
                                                unsigned short* __restrict__ Vt,
                                                const float* __restrict__ sqk) {
  __shared__ unsigned short tl[64][72];
  const int tid = threadIdx.x;
  const int blk = blockIdx.x;
  const int tt = blk & 15, bh = blk >> 4, b = bh >> 4, h = bh & 15;
  const int t0 = tt << 6;
  const int r = tid >> 2, seg = tid & 3;
  float sc[16];
#pragma unroll
  for (int c = 0; c < 16; ++c) sc[c] = sqk[h * 64 + seg * 16 + c] * 32.f;
  for (int which = 0; which < 2; ++which) {
    unsigned short* p = qkv + (long)(b * 1024 + t0 + r) * 3072 + which * 1024 + h * 64 + seg * 16;
    s8v x0 = *(const s8v*)p, x1 = *(const s8v*)(p + 8);
    float ss = 0.f;
#pragma unroll
    for (int c = 0; c < 8; ++c) {
      float a = b2f((unsigned short)x0[c]), bb = b2f((unsigned short)x1[c]);
      ss += a * a + bb * bb;
    }
    ss += __shfl_xor(ss, 1, 64);
    ss += __shfl_xor(ss, 2, 64);
    float rn = rsqrtf(ss);
#pragma unroll
    for (int c = 0; c < 8; ++c) {
      x0[c] = (short)f2b(b2f((unsigned short)x0[c]) * rn * sc[c]);
      x1[c] = (short)f2b(b2f((unsigned short)x1[c]) * rn * sc[c + 8]);
    }
    *(s8v*)p = x0; *(s8v*)(p + 8) = x1;
  }
  {
    const unsigned short* p = qkv + (long)(b * 1024 + t0 + r) * 3072 + 2048 + h * 64 + seg * 16;
    s8v v0 = *(const s8v*)p, v1 = *(const s8v*)(p + 8);
#pragma unroll
    for (int c = 0; c < 8; ++c) {
      tl[seg * 16 + c][r] = (unsigned short)v0[c];
      tl[seg * 16 + 8 + c][r] = (unsigned short)v1[c];
    }
  }
  __syncthreads();
  {
    const int d = tid >> 2, part = tid & 3;
    s8v o0 = *(const s8v*)(&tl[d][part * 16]);
    s8v o1 = *(const s8v*)(&tl[d][part * 16 + 8]);
    unsigned short* q = Vt + (long)(bh * 64 + d) * 1024 + t0 + part * 16;
    *(s8v*)q = o0; *(s8v*)(q + 8) = o1;
  }
}

// ---------------- flash attention (non-causal, bounded logits -> no running max) ----------------
__global__ __launch_bounds__(256) void attn(const unsigned short* __restrict__ qkv,
                                            const unsigned short* __restrict__ Vt,
                                            unsigned short* __restrict__ Y) {
  __shared__ unsigned short smem[33792];
  unsigned short* Klds = smem;
  unsigned short* Vlds = smem + 8192;
  unsigned short* Plds = smem + 16384;
  const int tid = threadIdx.x, lane = tid & 63, w = tid >> 6;
  const int quad = lane >> 4, lq = lane & 15;
  const int bh = blockIdx.x, b = bh >> 4, h = bh & 15;
  const int qt = blockIdx.y;
  const int e0 = tid << 3;
  const int c_lo = e0 >> 10, row_s = (e0 & 1023) >> 3;
  const int vc_lo = e0 >> 9, vd = (e0 & 511) >> 3;

  s8v qf[2][2];
#pragma unroll
  for (int i = 0; i < 2; ++i)
#pragma unroll
    for (int ks = 0; ks < 2; ++ks) {
      int row = qt * 128 + w * 32 + i * 16 + lq;
      qf[i][ks] = *(const s8v*)(qkv + (long)(b * 1024 + row) * 3072 + h * 64 + ks * 32 + quad * 8);
    }

  f4v o[2][4];
  float lp[2][4];
  f4v zero = {0.f, 0.f, 0.f, 0.f};
#pragma unroll
  for (int i = 0; i < 2; ++i) {
#pragma unroll
    for (int nf = 0; nf < 4; ++nf) o[i][nf] = zero;
#pragma unroll
    for (int r = 0; r < 4; ++r) lp[i][r] = 0.f;
  }

  const unsigned short* Kg = qkv + (long)(b * 1024 + row_s) * 3072 + 1024 + h * 64 + (c_lo << 3);
  const unsigned short* Vg = Vt + (long)(bh * 64 + vd) * 1024 + (vc_lo << 3);
  unsigned short* Pw = Plds + w * 4352;

  for (int kt0 = 0; kt0 < 1024; kt0 += 128) {
    __syncthreads();
#pragma unroll
    for (int it = 0; it < 4; ++it) {
      gl_lds16(Kg + (long)kt0 * 3072 + it * 16, Klds + it * 2048 + e0);
      gl_lds16(Vg + kt0 + it * 32, Vlds + it * 2048 + e0);
    }
    __syncthreads();
    f4v s[2][8];
#pragma unroll
    for (int i = 0; i < 2; ++i)
#pragma unroll
      for (int j = 0; j < 8; ++j) s[i][j] = zero;
#pragma unroll
    for (int ks = 0; ks < 2; ++ks)
#pragma unroll
      for (int j = 0; j < 8; ++j) {
        s8v kf = *(const s8v*)(Klds + (ks * 4 + quad) * 1024 + (j * 16 + lq) * 8);
        s[0][j] = __builtin_amdgcn_mfma_f32_16x16x32_bf16(qf[0][ks], kf, s[0][j], 0, 0, 0);
        s[1][j] = __builtin_amdgcn_mfma_f32_16x16x32_bf16(qf[1][ks], kf, s[1][j], 0, 0, 0);
      }
#pragma unroll
    for (int i = 0; i < 2; ++i)
#pragma unroll
      for (int j = 0; j < 8; ++j)
#pragma unroll
        for (int r = 0; r < 4; ++r) {
          float p = __builtin_amdgcn_exp2f(s[i][j][r] * 11.5415603f - 11.5415603f);
          lp[i][r] += p;
          Pw[(i * 16 + quad * 4 + r) * 136 + j * 16 + lq] = f2b(p);
        }
    s8v pf[2][4];
#pragma unroll
    for (int i = 0; i < 2; ++i)
#pragma unroll
      for (int ks = 0; ks < 4; ++ks)
        pf[i][ks] = *(const s8v*)(Pw + (i * 16 + lq) * 136 + ks * 32 + quad * 8);
#pragma unroll
    for (int nf = 0; nf < 4; ++nf)
#pragma unroll
      for (int ks = 0; ks < 4; ++ks) {
        s8v vf = *(const s8v*)(Vlds + (ks * 4 + quad) * 512 + (nf * 16 + lq) * 8);
        o[0][nf] = __builtin_amdgcn_mfma_f32_16x16x32_bf16(pf[0][ks], vf, o[0][nf], 0, 0, 0);
        o[1][nf] = __builtin_amdgcn_mfma_f32_16x16x32_bf16(pf[1][ks], vf, o[1][nf], 0, 0, 0);
      }
  }
#pragma unroll
  for (int i = 0; i < 2; ++i)
#pragma unroll
    for (int r = 0; r < 4; ++r) {
      float v = lp[i][r];
      v += __shfl_xor(v, 1, 64); v += __shfl_xor(v, 2, 64);
      v += __shfl_xor(v, 4, 64); v += __shfl_xor(v, 8, 64);
      lp[i][r] = 1.f / v;
    }
#pragma unroll
  for (int i = 0; i < 2; ++i)
#pragma unroll
    for (int nf = 0; nf < 4; ++nf)
#pragma unroll
      for (int r = 0; r < 4; ++r) {
        int row = qt * 128 + w * 32 + i * 16 + quad * 4 + r;
        Y[(long)(b * 1024 + row) * 1024 + h * 64 + nf * 16 + lq] = f2b(o[i][nf][r] * lp[i][r]);
      }
}

// ---------------- spherical-lerp residual: out = justnorm(A + |alpha*1.6|*(Bn - A)) ----------------
__global__ __launch_bounds__(256) void residual(
    const float* __restrict__ hin, const unsigned short* __restrict__ hbr,
    const float* __restrict__ alpha, float* __restrict__ outf,
    unsigned short* __restrict__ outb) {
  __shared__ float red[8];
  const int tid = threadIdx.x, lane = tid & 63, w = tid >> 6;
  const long base = (long)blockIdx.x * 1024;
  float hv[4], bvv[4];
  float s1 = 0.f, s2 = 0.f;
#pragma unroll
  for (int k = 0; k < 4; ++k) {
    int c = k * 256 + tid;
    hv[k] = hin[base + c];
    bvv[k] = b2f(hbr[base + c]);
    s1 += hv[k] * hv[k]; s2 += bvv[k] * bvv[k];
  }
#pragma unroll
  for (int m = 1; m < 64; m <<= 1) { s1 += __shfl_xor(s1, m, 64); s2 += __shfl_xor(s2, m, 64); }
  if (lane == 0) { red[w] = s1; red[4 + w] = s2; }
  __syncthreads();
  s1 = red[0] + red[1] + red[2] + red[3];
  s2 = red[4] + red[5] + red[6] + red[7];
  float rn1 = rsqrtf(s1), rn2 = rsqrtf(s2);
  float z[4], s3 = 0.f;
#pragma unroll
  for (int k = 0; k < 4; ++k) {
    int c = k * 256 + tid;
    float a = hv[k] * rn1;
    float lr = fabsf(alpha[c]) * 1.6f;
    float zz = a + lr * (bvv[k] * rn2 - a);
    z[k] = zz; s3 += zz * zz;
  }
#pragma unroll
  for (int m = 1; m < 64; m <<= 1) s3 += __shfl_xor(s3, m, 64);
  __syncthreads();
  if (lane == 0) red[w] = s3;
  __syncthreads();
  s3 = red[0] + red[1] + red[2] + red[3];
  float rn3 = rsqrtf(s3);
#pragma unroll
  for (int k = 0; k < 4; ++k) {
    int c = k * 256 + tid;
    float ov = z[k] * rn3;
    if (outf) outf[base + c] = ov;
    if (outb) outb[base + c] = f2b(ov);
  }
}

extern "C" void kernel_launch(void* const* d_in, const int* in_sizes, int n_in,
                              void* d_out, int out_size, void* d_ws, size_t ws_size,
                              hipStream_t stream) {
  const float* h   = (const float*)d_in[0];
  const float* Wq  = (const float*)d_in[1];
  const float* Wk  = (const float*)d_in[2];
  const float* Wv  = (const float*)d_in[3];
  const float* Wo  = (const float*)d_in[4];
  const float* Wfc = (const float*)d_in[5];
  const float* Wpj = (const float*)d_in[6];
  const float* sqk = (const float*)d_in[7];
  const float* suv = (const float*)d_in[8];
  const float* aat = (const float*)d_in[9];
  const float* aml = (const float*)d_in[10];
  float* out = (float*)d_out;  // reference output dtype is float32

  char* ws = (char*)d_ws;
  size_t off = 0;
  auto alloc = [&](size_t n) { char* p = ws + off; off += (n + 255) & ~(size_t)255; return p; };
  float* cs_q  = (float*)alloc(4096);
  float* cs_k  = (float*)alloc(4096);
  float* cs_v  = (float*)alloc(4096);
  float* cs_o  = (float*)alloc(4096);
  unsigned short* Wqkv_b = (unsigned short*)alloc(3ull * 1024 * 1024 * 2);
  unsigned short* Wo_b   = (unsigned short*)alloc(1024ull * 1024 * 2);
  unsigned short* Wfc_b  = (unsigned short*)alloc(8192ull * 1024 * 2);   // RAW (no col-norm)
  unsigned short* Wpj_b  = (unsigned short*)alloc(1024ull * 4096 * 2);   // RAW (no col-norm)
  unsigned short* slotC  = (unsigned short*)alloc(8192ull * 1024 * 2);   // h_b -> h_mlp
  unsigned short* slotD  = (unsigned short*)alloc(8192ull * 4096 * 2);   // qkv -> xmlp; hatt at +48MB
  unsigned short* slotE  = (unsigned short*)alloc(8192ull * 1024 * 2);   // Vt -> h2_b
  unsigned short* y_b    = (unsigned short*)alloc(8192ull * 1024 * 2);
  float*          h2_f   = (float*)alloc(8192ull * 1024 * 4);

  unsigned short* h_b    = slotC;
  unsigned short* hmlp_b = slotC;
  unsigned short* qkv_r  = slotD;
  unsigned short* xmlp   = slotD;
  unsigned short* hatt_b = slotD + 25165824;  // byte 48MB..64MB of slotD (qkv dead after attn)
  unsigned short* Vt     = slotE;
  unsigned short* h2_b   = slotE;

  hipMemsetAsync(ws, 0, 16384, stream);
  colsq<<<dim3(4, 16), 256, 0, stream>>>(Wq, cs_q, 1024);
  colsq<<<dim3(4, 16), 256, 0, stream>>>(Wk, cs_k, 1024);
  colsq<<<dim3(4, 16), 256, 0, stream>>>(Wv, cs_v, 1024);
  colsq<<<dim3(4, 16), 256, 0, stream>>>(Wo, cs_o, 1024);
  convw<<<1024, 256, 0, stream>>>(Wq, cs_q, Wqkv_b, 1023);
  convw<<<1024, 256, 0, stream>>>(Wk, cs_k, Wqkv_b + 1048576, 1023);
  convw<<<1024, 256, 0, stream>>>(Wv, cs_v, Wqkv_b + 2097152, 1023);
  convw<<<1024, 256, 0, stream>>>(Wo, cs_o, Wo_b, 1023);
  castf2b<<<8192, 256, 0, stream>>>(Wfc, Wfc_b);
  castf2b<<<4096, 256, 0, stream>>>(Wpj, Wpj_b);
  castf2b<<<8192, 256, 0, stream>>>(h, h_b);
  // qkv = h @ [Wq_n;Wk_n;Wv_n]^T
  gemm_bt<<<dim3(24, 64), 256, 0, stream>>>(h_b, Wqkv_b, qkv_r, 1024, 3072);
  qkv_norm<<<2048, 256, 0, stream>>>(qkv_r, Vt, sqk);
  attn<<<dim3(128, 8), 256, 0, stream>>>(qkv_r, Vt, y_b);
  // h_att = y @ Wo_n^T
  gemm_bt<<<dim3(8, 64), 256, 0, stream>>>(y_b, Wo_b, hatt_b, 1024, 1024);
  residual<<<8192, 256, 0, stream>>>(h, hatt_b, aat, h2_f, h2_b);
  // x_mlp = swiglu(h2 @ Wfc^T)  — 256x256-tile 4-deep pipelined kernel
  gemm_fc<<<1024, 512, 0, stream>>>(h2_b, Wfc_b, xmlp, suv);
  // h_mlp = x_mlp @ Wproj^T
  gemm_bt<<<dim3(8, 64), 256, 0, stream>>>(xmlp, Wpj_b, hmlp_b, 4096, 1024);
  // FINAL: write float32 to d_out
  residual<<<8192, 256, 0, stream>>>(h2_f, hmlp_b, aml, out, nullptr);
}

// Round 3
// 642.065 us; speedup vs baseline: 1.3521x; 1.0118x over previous
//
#include <hip/hip_runtime.h>

typedef __attribute__((ext_vector_type(8))) short s8v;
typedef __attribute__((ext_vector_type(4))) short s4v;
typedef __attribute__((ext_vector_type(4))) float f4v;

#define MFMA __builtin_amdgcn_mfma_f32_16x16x32_bf16

__device__ __forceinline__ float b2f(unsigned short b) {
  union { unsigned u; float f; } x; x.u = ((unsigned)b) << 16; return x.f;
}
__device__ __forceinline__ unsigned short f2b(float f) {
  union { float f; unsigned u; } x; x.f = f;
  unsigned r = x.u + 0x7fffu + ((x.u >> 16) & 1u);
  return (unsigned short)(r >> 16);
}
__device__ __forceinline__ void gl_lds16(const void* g, void* l) {
  __builtin_amdgcn_global_load_lds(
      (const __attribute__((address_space(1))) unsigned int*)g,
      (__attribute__((address_space(3))) unsigned int*)l, 16, 0, 0);
}

// ---------------- column-norm (sum of squares over rows) ----------------
__global__ void colsq(const float* __restrict__ W, float* __restrict__ out, int K) {
  int j = blockIdx.x * 256 + threadIdx.x;
  const float* p = W + (long)(blockIdx.y * 64) * K + j;
  float s = 0.f;
#pragma unroll 4
  for (int n = 0; n < 64; ++n) { float v = p[(long)n * K]; s += v * v; }
  atomicAdd(&out[j], s);
}

// ---------------- weight convert: bf16(W * rsqrt(colsum)) ----------------
__global__ void convw(const float* __restrict__ src, const float* __restrict__ cs,
                      unsigned short* __restrict__ dst, int Kmask) {
  long idx = ((long)blockIdx.x * 256 + threadIdx.x) << 2;
  float4 v = *(const float4*)(src + idx);
  int j = (int)(idx & (long)Kmask);
  s4v o;
  o[0] = (short)f2b(v.x * rsqrtf(cs[j]));
  o[1] = (short)f2b(v.y * rsqrtf(cs[j + 1]));
  o[2] = (short)f2b(v.z * rsqrtf(cs[j + 2]));
  o[3] = (short)f2b(v.w * rsqrtf(cs[j + 3]));
  *(s4v*)(dst + idx) = o;
}

__global__ void castf2b(const float* __restrict__ src, unsigned short* __restrict__ dst) {
  long idx = ((long)blockIdx.x * 256 + threadIdx.x) << 2;
  float4 v = *(const float4*)(src + idx);
  s4v o;
  o[0] = (short)f2b(v.x); o[1] = (short)f2b(v.y);
  o[2] = (short)f2b(v.z); o[3] = (short)f2b(v.w);
  *(s4v*)(dst + idx) = o;
}

// ---------------- 128x128 bf16 NT GEMM, 4-deep pipelined: C[m,n] = sum_k A[m,k]B[n,k] ----------------
__global__ __launch_bounds__(256) void gemm_bt(
    const unsigned short* __restrict__ A, const unsigned short* __restrict__ B,
    unsigned short* __restrict__ Cout, int K, int ldc) {
  __shared__ unsigned short smem[32768];  // 64 KB: 4 bufs x (A 8KB | B 8KB)
  const int tid = threadIdx.x, lane = tid & 63, w = tid >> 6;
  const int quad = lane >> 4, lq = lane & 15;
  const int wy = w >> 1, wx = w & 1;
  const int m0 = blockIdx.y << 7, n0 = blockIdx.x << 7;

  const int trow = tid >> 2;
  const int cb = ((tid & 3) ^ ((tid >> 3) & 3)) << 3;
  const unsigned short* Ag0 = A + (long)(m0 + trow) * K + cb;
  const unsigned short* Ag1 = A + (long)(m0 + 64 + trow) * K + cb;
  const unsigned short* Bg0 = B + (long)(n0 + trow) * K + cb;
  const unsigned short* Bg1 = B + (long)(n0 + 64 + trow) * K + cb;
  unsigned short* l0 = smem + (tid << 3);

  const int swz = ((lq >> 1) & 3) << 4;
  const int aoff = (wy * 64 + lq) * 64 + ((quad << 4) ^ swz);
  const int boff = 8192 + (wx * 64 + lq) * 64 + ((quad << 4) ^ swz);

  f4v acc[4][4];
  f4v zero = {0.f, 0.f, 0.f, 0.f};
#pragma unroll
  for (int i = 0; i < 4; ++i)
#pragma unroll
    for (int j = 0; j < 4; ++j) acc[i][j] = zero;

  auto stage = [&](int T) {
    const int bo = (T & 3) << 13;
    const int col = T << 5;
    gl_lds16(Ag0 + col, l0 + bo);
    gl_lds16(Ag1 + col, l0 + bo + 2048);
    gl_lds16(Bg0 + col, l0 + bo + 4096);
    gl_lds16(Bg1 + col, l0 + bo + 6144);
  };
  const char* sb = (const char*)smem;
  auto compute = [&](int kt) {
    const int bo = (kt & 3) << 14;
    s8v a[4], b[4];
#pragma unroll
    for (int i = 0; i < 4; ++i) a[i] = *(const s8v*)(sb + bo + aoff + i * 1024);
#pragma unroll
    for (int j = 0; j < 4; ++j) b[j] = *(const s8v*)(sb + bo + boff + j * 1024);
    __builtin_amdgcn_s_setprio(1);
#pragma unroll
    for (int i = 0; i < 4; ++i)
#pragma unroll
      for (int j = 0; j < 4; ++j)
        acc[i][j] = MFMA(a[i], b[j], acc[i][j], 0, 0, 0);
    __builtin_amdgcn_s_setprio(0);
  };

  const int nt = K >> 5;
  stage(0); stage(1); stage(2);
  for (int kt = 0; kt < nt - 2; ++kt) {
    asm volatile("s_waitcnt vmcnt(8)" ::: "memory");
    __builtin_amdgcn_s_barrier();
    asm volatile("" ::: "memory");
    if (kt < nt - 3) stage(kt + 3);
    compute(kt);
  }
  asm volatile("s_waitcnt vmcnt(4)" ::: "memory");
  __builtin_amdgcn_s_barrier();
  asm volatile("" ::: "memory");
  compute(nt - 2);
  asm volatile("s_waitcnt vmcnt(0)" ::: "memory");
  __builtin_amdgcn_s_barrier();
  asm volatile("" ::: "memory");
  compute(nt - 1);

  __syncthreads();
#pragma unroll
  for (int i = 0; i < 4; ++i)
#pragma unroll
    for (int j = 0; j < 4; ++j)
#pragma unroll
      for (int r = 0; r < 4; ++r) {
        int row = wy * 64 + i * 16 + quad * 4 + r;
        int col = wx * 64 + j * 16 + lq;
        smem[row * 136 + col] = f2b(acc[i][j][r]);
      }
  __syncthreads();
#pragma unroll
  for (int it = 0; it < 8; ++it) {
    int row = it * 16 + (tid >> 4);
    int col = (tid & 15) << 3;
    s8v v = *(const s8v*)(smem + row * 136 + col);
    *(s8v*)(Cout + (long)(m0 + row) * ldc + n0 + col) = v;
  }
}

// ---------------- Wfc GEMM fused with SwiGLU: 256x256 tile, BK=64, 8-phase schedule ----------------
// 512 thr = 8 waves (wy 2 x wx 4). LDS 128KB = 2 K-tile bufs x {A[256][64] | u[128][64] | v[128][64]}.
// 4 phases/K-tile: P0{rd A0-3,u; stA(t+1,1); bar; 16 MFMA aU[0-3]} P1{rd v; stB(t+2,u); 16 aV[0-3]}
// P2{rd A4-7; stB(t+2,v); 16 aU[4-7]} P3{stA(t+2,0); 16 aV[4-7]; vmcnt(6); bar}.
// Stage order lands each region's overwrite >=1 closed phase after its last read.
// Swizzle: LDS[row][slot] holds global slot^(row&7) (16B slots); read addr XORs (lq&7)<<4.
// NOTE: suv loads deferred to epilogue — stray global loads would corrupt vmcnt counts.
__global__ __launch_bounds__(512, 2) void gemm_fc(
    const unsigned short* __restrict__ A, const unsigned short* __restrict__ B,
    unsigned short* __restrict__ X, const float* __restrict__ suv) {
  __shared__ unsigned short smem[65536];  // 128 KB
  const int tid = threadIdx.x, lane = tid & 63, w = tid >> 6;
  const int quad = lane >> 4, lq = lane & 15;
  const int wy = w >> 2, wx = w & 3;
  const int bid = blockIdx.x;
  const int xr = bid & 7, xq = bid >> 3;  // XCD chunk, m-minor (B panel L2-reused 4x)
  const int m0 = ((xr << 2) | (xq & 3)) << 8;
  const int n0 = (xq >> 2) << 7;

  // stage side: linear LDS dest, inverse-swizzled global column
  const int trow = tid >> 3;                       // 0..63
  const int scol = ((tid & 7) ^ (trow & 7)) << 3;  // bf16 col within 64
  const unsigned short* pA = A + (long)(m0 + trow) * 1024 + scol;
  const unsigned short* pB = B + (long)(n0 + trow) * 1024 + scol;
  unsigned short* ldst = smem + tid * 8;

  auto stA = [&](int tile, int half) {  // A rows half*128..+127 -> region A0/A1
    const int base = (tile & 1) * 32768 + half * 8192;  // halfwords
    const unsigned short* src = pA + (long)half * 131072 + (tile << 6);
    gl_lds16(src, ldst + base);
    gl_lds16(src + 65536, ldst + base + 4096);
  };
  auto stB = [&](int tile, int vh) {  // vh0=u (B rows n0..), vh1=v (B rows 4096+n0..)
    const int base = (tile & 1) * 32768 + 16384 + vh * 8192;
    const unsigned short* src = pB + (long)vh * 4194304 + (tile << 6);
    gl_lds16(src, ldst + base);
    gl_lds16(src + 65536, ldst + base + 4096);
  };

  // read side (byte offsets within buf): row*128 + ((kk*64+quad*16) ^ ((row&7)<<4))
  const int rsw = (lq & 7) << 4;
  const int c0 = (quad * 16) ^ rsw;
  const int c1 = (64 + quad * 16) ^ rsw;
  const int aro = wy * 16384 + lq * 128;         // + m*2048 + c{0,1}
  const int uro = 32768 + (wx * 32 + lq) * 128;  // + j*2048 + c{0,1}
  const int vro = 49152 + (wx * 32 + lq) * 128;
  const char* sb = (const char*)smem;

  f4v aU[8][2], aV[8][2];
  f4v zero = {0.f, 0.f, 0.f, 0.f};
#pragma unroll
  for (int m = 0; m < 8; ++m)
#pragma unroll
    for (int j = 0; j < 2; ++j) { aU[m][j] = zero; aV[m][j] = zero; }

  s8v av[4][2], uf[2][2], vg[2][2];

  auto tile_phases = [&](int t, int bufB) {
    // ---------------- P0 ----------------
#pragma unroll
    for (int m = 0; m < 4; ++m) {
      av[m][0] = *(const s8v*)(sb + bufB + aro + m * 2048 + c0);
      av[m][1] = *(const s8v*)(sb + bufB + aro + m * 2048 + c1);
    }
#pragma unroll
    for (int j = 0; j < 2; ++j) {
      uf[j][0] = *(const s8v*)(sb + bufB + uro + j * 2048 + c0);
      uf[j][1] = *(const s8v*)(sb + bufB + uro + j * 2048 + c1);
    }
    if (t < 15) stA(t + 1, 1);
    __builtin_amdgcn_s_barrier();
    asm volatile("" ::: "memory");
    __builtin_amdgcn_s_setprio(1);
#pragma unroll
    for (int m = 0; m < 4; ++m)
#pragma unroll
      for (int j = 0; j < 2; ++j) {
        aU[m][j] = MFMA(av[m][0], uf[j][0], aU[m][j], 0, 0, 0);
        aU[m][j] = MFMA(av[m][1], uf[j][1], aU[m][j], 0, 0, 0);
      }
    __builtin_amdgcn_s_setprio(0);
    asm volatile("" ::: "memory");
    __builtin_amdgcn_s_barrier();
    asm volatile("" ::: "memory");
    // ---------------- P1 ----------------
#pragma unroll
    for (int j = 0; j < 2; ++j) {
      vg[j][0] = *(const s8v*)(sb + bufB + vro + j * 2048 + c0);
      vg[j][1] = *(const s8v*)(sb + bufB + vro + j * 2048 + c1);
    }
    if (t < 14) stB(t + 2, 0);
    __builtin_amdgcn_s_barrier();
    asm volatile("" ::: "memory");
    __builtin_amdgcn_s_setprio(1);
#pragma unroll
    for (int m = 0; m < 4; ++m)
#pragma unroll
      for (int j = 0; j < 2; ++j) {
        aV[m][j] = MFMA(av[m][0], vg[j][0], aV[m][j], 0, 0, 0);
        aV[m][j] = MFMA(av[m][1], vg[j][1], aV[m][j], 0, 0, 0);
      }
    __builtin_amdgcn_s_setprio(0);
    asm volatile("" ::: "memory");
    __builtin_amdgcn_s_barrier();
    asm volatile("" ::: "memory");
    // ---------------- P2 ----------------
#pragma unroll
    for (int m = 0; m < 4; ++m) {
      av[m][0] = *(const s8v*)(sb + bufB + aro + (m + 4) * 2048 + c0);
      av[m][1] = *(const s8v*)(sb + bufB + aro + (m + 4) * 2048 + c1);
    }
    if (t < 14) stB(t + 2, 1);
    __builtin_amdgcn_s_barrier();
    asm volatile("" ::: "memory");
    __builtin_amdgcn_s_setprio(1);
#pragma unroll
    for (int m = 0; m < 4; ++m)
#pragma unroll
      for (int j = 0; j < 2; ++j) {
        aU[m + 4][j] = MFMA(av[m][0], uf[j][0], aU[m + 4][j], 0, 0, 0);
        aU[m + 4][j] = MFMA(av[m][1], uf[j][1], aU[m + 4][j], 0, 0, 0);
      }
    __builtin_amdgcn_s_setprio(0);
    asm volatile("" ::: "memory");
    __builtin_amdgcn_s_barrier();
    asm volatile("" ::: "memory");
    // ---------------- P3 ----------------
    if (t < 14) stA(t + 2, 0);
    __builtin_amdgcn_s_barrier();
    asm volatile("" ::: "memory");
    __builtin_amdgcn_s_setprio(1);
#pragma unroll
    for (int m = 0; m < 4; ++m)
#pragma unroll
      for (int j = 0; j < 2; ++j) {
        aV[m + 4][j] = MFMA(av[m][0], vg[j][0], aV[m + 4][j], 0, 0, 0);
        aV[m + 4][j] = MFMA(av[m][1], vg[j][1], aV[m + 4][j], 0, 0, 0);
      }
    __builtin_amdgcn_s_setprio(0);
    if (t < 14) { asm volatile("s_waitcnt vmcnt(6)" ::: "memory"); }
    else if (t == 14) { asm volatile("s_waitcnt vmcnt(0)" ::: "memory"); }
    asm volatile("" ::: "memory");
    __builtin_amdgcn_s_barrier();
    asm volatile("" ::: "memory");
  };

  // prologue: tile0 {u,v,A0,A1}, tile1 {u,v,A0} = 7 half-tiles (14 loads)
  stB(0, 0); stB(0, 1); stA(0, 0); stA(0, 1);
  stB(1, 0); stB(1, 1); stA(1, 0);
  asm volatile("s_waitcnt vmcnt(6)" ::: "memory");
  __builtin_amdgcn_s_barrier();
  asm volatile("" ::: "memory");

  for (int tt = 0; tt < 8; ++tt) {
    tile_phases(tt * 2, 0);
    tile_phases(tt * 2 + 1, 65536);
  }

  // epilogue: load scales now (after all vmcnt counting is done)
  float su[2], sv[2];
#pragma unroll
  for (int j = 0; j < 2; ++j) {
    su[j] = suv[n0 + wx * 32 + j * 16 + lq] * 32.f;
    sv[j] = suv[4096 + n0 + wx * 32 + j * 16 + lq] * 32.f;
  }
  __syncthreads();
#pragma unroll
  for (int m = 0; m < 8; ++m)
#pragma unroll
    for (int j = 0; j < 2; ++j)
#pragma unroll
      for (int r = 0; r < 4; ++r) {
        int row = wy * 128 + m * 16 + quad * 4 + r;
        int col = wx * 32 + j * 16 + lq;
        float uu = aU[m][j][r] * su[j];
        float vv = aV[m][j][r] * sv[j];
        float sig = 1.f / (1.f + __builtin_amdgcn_exp2f(vv * -1.44269504f));
        smem[row * 132 + col] = f2b(uu * vv * sig);
      }
  __syncthreads();
  {
    const int row = tid >> 1, half = tid & 1;
    unsigned short* dst = X + (long)(m0 + row) * 4096 + n0 + half * 64;
    const unsigned short* srcr = smem + row * 132 + half * 64;
#pragma unroll
    for (int s = 0; s < 8; ++s)
      *(s8v*)(dst + s * 8) = *(const s8v*)(srcr + s * 8);
  }
}

// ---------------- qkv post-process: justnorm q,k (in-place, *sqk*32), V -> Vt[BH,D,T] ----------------
__global__ __launch_bounds__(256) void qkv_norm(unsigned short* __restrict__ qkv,
                                                unsigned short* __restrict__ Vt,
                                                const float* __restrict__ sqk) {
  __shared__ unsigned short tl[64][72];
  const int tid = threadIdx.x;
  const int blk = blockIdx.x;
  const int tt = blk & 15, bh = blk >> 4, b = bh >> 4, h = bh & 15;
  const int t0 = tt << 6;
  const int r = tid >> 2, seg = tid & 3;
  float sc[16];
#pragma unroll
  for (int c = 0; c < 16; ++c) sc[c] = sqk[h * 64 + seg * 16 + c] * 32.f;
  for (int which = 0; which < 2; ++which) {
    unsigned short* p = qkv + (long)(b * 1024 + t0 + r) * 3072 + which * 1024 + h * 64 + seg * 16;
    s8v x0 = *(const s8v*)p, x1 = *(const s8v*)(p + 8);
    float ss = 0.f;
#pragma unroll
    for (int c = 0; c < 8; ++c) {
      float a = b2f((unsigned short)x0[c]), bb = b2f((unsigned short)x1[c]);
      ss += a * a + bb * bb;
    }
    ss += __shfl_xor(ss, 1, 64);
    ss += __shfl_xor(ss, 2, 64);
    float rn = rsqrtf(ss);
#pragma unroll
    for (int c = 0; c < 8; ++c) {
      x0[c] = (short)f2b(b2f((unsigned short)x0[c]) * rn * sc[c]);
      x1[c] = (short)f2b(b2f((unsigned short)x1[c]) * rn * sc[c + 8]);
    }
    *(s8v*)p = x0; *(s8v*)(p + 8) = x1;
  }
  {
    const unsigned short* p = qkv + (long)(b * 1024 + t0 + r) * 3072 + 2048 + h * 64 + seg * 16;
    s8v v0 = *(const s8v*)p, v1 = *(const s8v*)(p + 8);
#pragma unroll
    for (int c = 0; c < 8; ++c) {
      tl[seg * 16 + c][r] = (unsigned short)v0[c];
      tl[seg * 16 + 8 + c][r] = (unsigned short)v1[c];
    }
  }
  __syncthreads();
  {
    const int d = tid >> 2, part = tid & 3;
    s8v o0 = *(const s8v*)(&tl[d][part * 16]);
    s8v o1 = *(const s8v*)(&tl[d][part * 16 + 8]);
    unsigned short* q = Vt + (long)(bh * 64 + d) * 1024 + t0 + part * 16;
    *(s8v*)q = o0; *(s8v*)(q + 8) = o1;
  }
}

// ---------------- flash attention (non-causal, bounded logits -> no running max) ----------------
__global__ __launch_bounds__(256) void attn(const unsigned short* __restrict__ qkv,
                                            const unsigned short* __restrict__ Vt,
                                            unsigned short* __restrict__ Y) {
  __shared__ unsigned short smem[33792];
  unsigned short* Klds = smem;
  unsigned short* Vlds = smem + 8192;
  unsigned short* Plds = smem + 16384;
  const int tid = threadIdx.x, lane = tid & 63, w = tid >> 6;
  const int quad = lane >> 4, lq = lane & 15;
  const int bh = blockIdx.x, b = bh >> 4, h = bh & 15;
  const int qt = blockIdx.y;
  const int e0 = tid << 3;
  const int c_lo = e0 >> 10, row_s = (e0 & 1023) >> 3;
  const int vc_lo = e0 >> 9, vd = (e0 & 511) >> 3;

  s8v qf[2][2];
#pragma unroll
  for (int i = 0; i < 2; ++i)
#pragma unroll
    for (int ks = 0; ks < 2; ++ks) {
      int row = qt * 128 + w * 32 + i * 16 + lq;
      qf[i][ks] = *(const s8v*)(qkv + (long)(b * 1024 + row) * 3072 + h * 64 + ks * 32 + quad * 8);
    }

  f4v o[2][4];
  float lp[2][4];
  f4v zero = {0.f, 0.f, 0.f, 0.f};
#pragma unroll
  for (int i = 0; i < 2; ++i) {
#pragma unroll
    for (int nf = 0; nf < 4; ++nf) o[i][nf] = zero;
#pragma unroll
    for (int r = 0; r < 4; ++r) lp[i][r] = 0.f;
  }

  const unsigned short* Kg = qkv + (long)(b * 1024 + row_s) * 3072 + 1024 + h * 64 + (c_lo << 3);
  const unsigned short* Vg = Vt + (long)(bh * 64 + vd) * 1024 + (vc_lo << 3);
  unsigned short* Pw = Plds + w * 4352;

  for (int kt0 = 0; kt0 < 1024; kt0 += 128) {
    __syncthreads();
#pragma unroll
    for (int it = 0; it < 4; ++it) {
      gl_lds16(Kg + (long)kt0 * 3072 + it * 16, Klds + it * 2048 + e0);
      gl_lds16(Vg + kt0 + it * 32, Vlds + it * 2048 + e0);
    }
    __syncthreads();
    f4v s[2][8];
#pragma unroll
    for (int i = 0; i < 2; ++i)
#pragma unroll
      for (int j = 0; j < 8; ++j) s[i][j] = zero;
#pragma unroll
    for (int ks = 0; ks < 2; ++ks)
#pragma unroll
      for (int j = 0; j < 8; ++j) {
        s8v kf = *(const s8v*)(Klds + (ks * 4 + quad) * 1024 + (j * 16 + lq) * 8);
        s[0][j] = MFMA(qf[0][ks], kf, s[0][j], 0, 0, 0);
        s[1][j] = MFMA(qf[1][ks], kf, s[1][j], 0, 0, 0);
      }
#pragma unroll
    for (int i = 0; i < 2; ++i)
#pragma unroll
      for (int j = 0; j < 8; ++j)
#pragma unroll
        for (int r = 0; r < 4; ++r) {
          float p = __builtin_amdgcn_exp2f(s[i][j][r] * 11.5415603f - 11.5415603f);
          lp[i][r] += p;
          Pw[(i * 16 + quad * 4 + r) * 136 + j * 16 + lq] = f2b(p);
        }
    s8v pf[2][4];
#pragma unroll
    for (int i = 0; i < 2; ++i)
#pragma unroll
      for (int ks = 0; ks < 4; ++ks)
        pf[i][ks] = *(const s8v*)(Pw + (i * 16 + lq) * 136 + ks * 32 + quad * 8);
#pragma unroll
    for (int nf = 0; nf < 4; ++nf)
#pragma unroll
      for (int ks = 0; ks < 4; ++ks) {
        s8v vf = *(const s8v*)(Vlds + (ks * 4 + quad) * 512 + (nf * 16 + lq) * 8);
        o[0][nf] = MFMA(pf[0][ks], vf, o[0][nf], 0, 0, 0);
        o[1][nf] = MFMA(pf[1][ks], vf, o[1][nf], 0, 0, 0);
      }
  }
#pragma unroll
  for (int i = 0; i < 2; ++i)
#pragma unroll
    for (int r = 0; r < 4; ++r) {
      float v = lp[i][r];
      v += __shfl_xor(v, 1, 64); v += __shfl_xor(v, 2, 64);
      v += __shfl_xor(v, 4, 64); v += __shfl_xor(v, 8, 64);
      lp[i][r] = 1.f / v;
    }
#pragma unroll
  for (int i = 0; i < 2; ++i)
#pragma unroll
    for (int nf = 0; nf < 4; ++nf)
#pragma unroll
      for (int r = 0; r < 4; ++r) {
        int row = qt * 128 + w * 32 + i * 16 + quad * 4 + r;
        Y[(long)(b * 1024 + row) * 1024 + h * 64 + nf * 16 + lq] = f2b(o[i][nf][r] * lp[i][r]);
      }
}

// ---------------- spherical-lerp residual: out = justnorm(A + |alpha*1.6|*(Bn - A)) ----------------
__global__ __launch_bounds__(256) void residual(
    const float* __restrict__ hin, const unsigned short* __restrict__ hbr,
    const float* __restrict__ alpha, float* __restrict__ outf,
    unsigned short* __restrict__ outb) {
  __shared__ float red[8];
  const int tid = threadIdx.x, lane = tid & 63, w = tid >> 6;
  const long base = (long)blockIdx.x * 1024;
  float hv[4], bvv[4];
  float s1 = 0.f, s2 = 0.f;
#pragma unroll
  for (int k = 0; k < 4; ++k) {
    int c = k * 256 + tid;
    hv[k] = hin[base + c];
    bvv[k] = b2f(hbr[base + c]);
    s1 += hv[k] * hv[k]; s2 += bvv[k] * bvv[k];
  }
#pragma unroll
  for (int m = 1; m < 64; m <<= 1) { s1 += __shfl_xor(s1, m, 64); s2 += __shfl_xor(s2, m, 64); }
  if (lane == 0) { red[w] = s1; red[4 + w] = s2; }
  __syncthreads();
  s1 = red[0] + red[1] + red[2] + red[3];
  s2 = red[4] + red[5] + red[6] + red[7];
  float rn1 = rsqrtf(s1), rn2 = rsqrtf(s2);
  float z[4], s3 = 0.f;
#pragma unroll
  for (int k = 0; k < 4; ++k) {
    int c = k * 256 + tid;
    float a = hv[k] * rn1;
    float lr = fabsf(alpha[c]) * 1.6f;
    float zz = a + lr * (bvv[k] * rn2 - a);
    z[k] = zz; s3 += zz * zz;
  }
#pragma unroll
  for (int m = 1; m < 64; m <<= 1) s3 += __shfl_xor(s3, m, 64);
  __syncthreads();
  if (lane == 0) red[w] = s3;
  __syncthreads();
  s3 = red[0] + red[1] + red[2] + red[3];
  float rn3 = rsqrtf(s3);
#pragma unroll
  for (int k = 0; k < 4; ++k) {
    int c = k * 256 + tid;
    float ov = z[k] * rn3;
    if (outf) outf[base + c] = ov;
    if (outb) outb[base + c] = f2b(ov);
  }
}

extern "C" void kernel_launch(void* const* d_in, const int* in_sizes, int n_in,
                              void* d_out, int out_size, void* d_ws, size_t ws_size,
                              hipStream_t stream) {
  const float* h   = (const float*)d_in[0];
  const float* Wq  = (const float*)d_in[1];
  const float* Wk  = (const float*)d_in[2];
  const float* Wv  = (const float*)d_in[3];
  const float* Wo  = (const float*)d_in[4];
  const float* Wfc = (const float*)d_in[5];
  const float* Wpj = (const float*)d_in[6];
  const float* sqk = (const float*)d_in[7];
  const float* suv = (const float*)d_in[8];
  const float* aat = (const float*)d_in[9];
  const float* aml = (const float*)d_in[10];
  float* out = (float*)d_out;  // reference output dtype is float32

  char* ws = (char*)d_ws;
  size_t off = 0;
  auto alloc = [&](size_t n) { char* p = ws + off; off += (n + 255) & ~(size_t)255; return p; };
  float* cs_q  = (float*)alloc(4096);
  float* cs_k  = (float*)alloc(4096);
  float* cs_v  = (float*)alloc(4096);
  float* cs_o  = (float*)alloc(4096);
  unsigned short* Wqkv_b = (unsigned short*)alloc(3ull * 1024 * 1024 * 2);
  unsigned short* Wo_b   = (unsigned short*)alloc(1024ull * 1024 * 2);
  unsigned short* Wfc_b  = (unsigned short*)alloc(8192ull * 1024 * 2);   // RAW (no col-norm)
  unsigned short* Wpj_b  = (unsigned short*)alloc(1024ull * 4096 * 2);   // RAW (no col-norm)
  unsigned short* slotC  = (unsigned short*)alloc(8192ull * 1024 * 2);   // h_b -> h_mlp
  unsigned short* slotD  = (unsigned short*)alloc(8192ull * 4096 * 2);   // qkv -> xmlp; hatt at +48MB
  unsigned short* slotE  = (unsigned short*)alloc(8192ull * 1024 * 2);   // Vt -> h2_b
  unsigned short* y_b    = (unsigned short*)alloc(8192ull * 1024 * 2);
  float*          h2_f   = (float*)alloc(8192ull * 1024 * 4);

  unsigned short* h_b    = slotC;
  unsigned short* hmlp_b = slotC;
  unsigned short* qkv_r  = slotD;
  unsigned short* xmlp   = slotD;
  unsigned short* hatt_b = slotD + 25165824;  // byte 48MB..64MB of slotD (qkv dead after attn)
  unsigned short* Vt     = slotE;
  unsigned short* h2_b   = slotE;

  hipMemsetAsync(ws, 0, 16384, stream);
  colsq<<<dim3(4, 16), 256, 0, stream>>>(Wq, cs_q, 1024);
  colsq<<<dim3(4, 16), 256, 0, stream>>>(Wk, cs_k, 1024);
  colsq<<<dim3(4, 16), 256, 0, stream>>>(Wv, cs_v, 1024);
  colsq<<<dim3(4, 16), 256, 0, stream>>>(Wo, cs_o, 1024);
  convw<<<1024, 256, 0, stream>>>(Wq, cs_q, Wqkv_b, 1023);
  convw<<<1024, 256, 0, stream>>>(Wk, cs_k, Wqkv_b + 1048576, 1023);
  convw<<<1024, 256, 0, stream>>>(Wv, cs_v, Wqkv_b + 2097152, 1023);
  convw<<<1024, 256, 0, stream>>>(Wo, cs_o, Wo_b, 1023);
  castf2b<<<8192, 256, 0, stream>>>(Wfc, Wfc_b);
  castf2b<<<4096, 256, 0, stream>>>(Wpj, Wpj_b);
  castf2b<<<8192, 256, 0, stream>>>(h, h_b);
  // qkv = h @ [Wq_n;Wk_n;Wv_n]^T
  gemm_bt<<<dim3(24, 64), 256, 0, stream>>>(h_b, Wqkv_b, qkv_r, 1024, 3072);
  qkv_norm<<<2048, 256, 0, stream>>>(qkv_r, Vt, sqk);
  attn<<<dim3(128, 8), 256, 0, stream>>>(qkv_r, Vt, y_b);
  // h_att = y @ Wo_n^T
  gemm_bt<<<dim3(8, 64), 256, 0, stream>>>(y_b, Wo_b, hatt_b, 1024, 1024);
  residual<<<8192, 256, 0, stream>>>(h, hatt_b, aat, h2_f, h2_b);
  // x_mlp = swiglu(h2 @ Wfc^T)  — 256x256-tile 8-phase pipelined kernel
  gemm_fc<<<1024, 512, 0, stream>>>(h2_b, Wfc_b, xmlp, suv);
  // h_mlp = x_mlp @ Wproj^T
  gemm_bt<<<dim3(8, 64), 256, 0, stream>>>(xmlp, Wpj_b, hmlp_b, 4096, 1024);
  // FINAL: write float32 to d_out
  residual<<<8192, 256, 0, stream>>>(h2_f, hmlp_b, aml, out, nullptr);
}